// Round 1
// baseline (303.679 us; speedup 1.0000x reference)
//
#include <hip/hip_runtime.h>
#include <hip/hip_bf16.h>

#define INFEAT 4096
#define OUTFEAT 11008
#define TOKENS 2048

typedef int v4i __attribute__((ext_vector_type(4)));
typedef __bf16 bf16_t;
typedef bf16_t bf16x4 __attribute__((ext_vector_type(4)));
typedef bf16_t bf16x8 __attribute__((ext_vector_type(8)));
typedef float f32x4 __attribute__((ext_vector_type(4)));

__device__ __forceinline__ void async_copy16(const void* g, void* l) {
    __builtin_amdgcn_global_load_lds((const __attribute__((address_space(1))) void*)g,
                                     (__attribute__((address_space(3))) void*)l,
                                     16, 0, 0);
}

// ---- fused pre-pass: blocks [0,2752) transpose weights (16B/lane loads),
// ---- blocks [2752,4800) do per-token i8 quantization of x.
__global__ __launch_bounds__(256) void prep(
    const float* __restrict__ x, const unsigned int* __restrict__ qw,
    unsigned int* __restrict__ xq, float* __restrict__ xscale, int* __restrict__ xsum,
    unsigned char* __restrict__ wt)
{
    __shared__ unsigned int Tw[64 * 64];   // 16 KB transpose staging
    __shared__ float smax[4];
    __shared__ int ssum[4];
    const int tid = threadIdx.x;

    if (blockIdx.x < 2752) {
        // ---------------- weight transpose: qw[kp][n] -> wt[n][k] bytes (^0x80)
        const int bid = blockIdx.x;
        const int n0  = (bid % 172) * 64;
        const int kp0 = (bid / 172) * 64;
        const int tn4 = tid & 15;          // uint4 index along n
        const int kb  = tid >> 4;          // 0..15
        #pragma unroll
        for (int it = 0; it < 4; ++it) {
            const int kp = kb + it * 16;   // 0..63, kp>>2 wave-uniform
            uint4 q = *(const uint4*)&qw[(size_t)(kp0 + kp) * OUTFEAT + n0 + tn4 * 4];
            q.x ^= 0x80808080u; q.y ^= 0x80808080u; q.z ^= 0x80808080u; q.w ^= 0x80808080u;
            const int ks = kp >> 2, kq = kp & 3;
            const int n = tn4 * 4;
            Tw[(n + 0) * 64 + ((ks ^ ((n + 0) & 15)) << 2) + kq] = q.x;
            Tw[(n + 1) * 64 + ((ks ^ ((n + 1) & 15)) << 2) + kq] = q.y;
            Tw[(n + 2) * 64 + ((ks ^ ((n + 2) & 15)) << 2) + kq] = q.z;
            Tw[(n + 3) * 64 + ((ks ^ ((n + 3) & 15)) << 2) + kq] = q.w;
        }
        __syncthreads();
        #pragma unroll
        for (int i = 0; i < 4; ++i) {
            const int flat = i * 256 + tid;
            const int n = flat >> 4;       // 0..63
            const int c = flat & 15;       // 16B chunk within 256B row
            uint4 v = *(const uint4*)&Tw[n * 64 + ((c ^ (n & 15)) * 4)];
            *(uint4*)&wt[(size_t)(n0 + n) * INFEAT + (size_t)kp0 * 4 + c * 16] = v;
        }
    } else {
        // ---------------- per-token i8 quantization
        const int row = blockIdx.x - 2752;
        const int lane = tid & 63, wid = tid >> 6;
        const float* xr = x + (size_t)row * INFEAT;

        float4 v[4];
        #pragma unroll
        for (int i = 0; i < 4; ++i) v[i] = *(const float4*)&xr[tid * 16 + i * 4];

        float am = 0.f;
        #pragma unroll
        for (int i = 0; i < 4; ++i)
            am = fmaxf(am, fmaxf(fmaxf(fabsf(v[i].x), fabsf(v[i].y)),
                                 fmaxf(fabsf(v[i].z), fabsf(v[i].w))));
        #pragma unroll
        for (int o = 32; o > 0; o >>= 1) am = fmaxf(am, __shfl_xor(am, o, 64));
        if (lane == 0) smax[wid] = am;
        __syncthreads();
        am = fmaxf(fmaxf(smax[0], smax[1]), fmaxf(smax[2], smax[3]));
        const float inv = am > 0.f ? 127.0f / am : 0.f;
        const float sc  = am > 0.f ? am / 127.0f : 0.f;

        int lsum = 0;
        unsigned int pk[4];
        #pragma unroll
        for (int i = 0; i < 4; ++i) {
            int q0 = (int)rintf(fminf(fmaxf(v[i].x * inv, -127.f), 127.f));
            int q1 = (int)rintf(fminf(fmaxf(v[i].y * inv, -127.f), 127.f));
            int q2 = (int)rintf(fminf(fmaxf(v[i].z * inv, -127.f), 127.f));
            int q3 = (int)rintf(fminf(fmaxf(v[i].w * inv, -127.f), 127.f));
            lsum += q0 + q1 + q2 + q3;
            pk[i] = (q0 & 255) | ((q1 & 255) << 8) | ((q2 & 255) << 16) | ((unsigned)(q3 & 255) << 24);
        }
        *(uint4*)&xq[(size_t)row * (INFEAT / 4) + tid * 4] = *(uint4*)pk;

        #pragma unroll
        for (int o = 32; o > 0; o >>= 1) lsum += __shfl_xor(lsum, o, 64);
        if (lane == 0) ssum[wid] = lsum;
        __syncthreads();
        if (tid == 0) {
            xsum[row] = ssum[0] + ssum[1] + ssum[2] + ssum[3];
            xscale[row] = sc;
        }
    }
}

// ---- main GEMM: i8 MFMA, 256x128 tile, 8 waves (4M x 2N), BK = 128 bytes.
// ---- 3-deep LDS pipeline (144 KB), counted vmcnt(6) per K-tile (T3+T4),
// ---- raw s_barrier + setprio around MFMA clusters (T5).
// ---- Fragment swizzle / staging identical to verified 2-phase kernel (0 conflicts).
// ---- Grid: bid&7 = m-tile -> each XCD pins one 1MB A-panel in its L2.
#define MFMA_I8(d, a, b) d = __builtin_amdgcn_mfma_i32_16x16x64_i8(a, b, d, 0, 0, 0)

__global__ __launch_bounds__(512, 2) void q3gemm_i8p(
    const unsigned char* __restrict__ xqb, const unsigned char* __restrict__ wt,
    const float* __restrict__ scales, const int* __restrict__ zeros,
    const float* __restrict__ bias, const float* __restrict__ xscale,
    const int* __restrict__ xsum, float* __restrict__ out)
{
    __shared__ unsigned char Als[3][256 * 128];   // 96 KB
    __shared__ unsigned char Bls[3][128 * 128];   // 48 KB

    const int tid  = threadIdx.x;
    const int wid  = tid >> 6, lane = tid & 63;
    const int m0 = (blockIdx.x & 7) * 256;
    const int n0 = (blockIdx.x >> 3) * 128;
    const int wm = (wid & 3) * 64;   // wave's 64-row slice of 256
    const int wn = (wid >> 2) * 64;  // wave's 64-col slice of 128
    const int lr = lane & 15, lq = lane >> 4;
    const int rsub = lane >> 3, sl = lane & 7;

    const unsigned char* aSrc = xqb + (size_t)m0 * INFEAT;
    const unsigned char* bSrc = wt  + (size_t)n0 * INFEAT;

    v4i acc[4][4];
    #pragma unroll
    for (int i = 0; i < 4; ++i)
        #pragma unroll
        for (int j = 0; j < 4; ++j) acc[i][j] = (v4i){0, 0, 0, 0};

#define STAGE_A(T, C, P) do {                                                        \
    const int r_ = wid * 32 + (P) * 8 + rsub;                                        \
    const int s_ = sl ^ (r_ & 7);                                                    \
    async_copy16(&aSrc[(size_t)r_ * INFEAT + (T) * 128 + s_ * 16],                   \
                 &Als[C][(wid * 32 + (P) * 8) * 128]);                               \
} while (0)
#define STAGE_B(T, C, P) do {                                                        \
    const int r_ = wid * 16 + (P) * 8 + rsub;                                        \
    const int s_ = sl ^ (r_ & 7);                                                    \
    async_copy16(&bSrc[(size_t)r_ * INFEAT + (T) * 128 + s_ * 16],                   \
                 &Bls[C][(wid * 16 + (P) * 8) * 128]);                               \
} while (0)

    // prologue: fully stage K-tiles 0 and 1 (6 loads each, per thread)
    STAGE_A(0, 0, 0); STAGE_A(0, 0, 1); STAGE_A(0, 0, 2); STAGE_A(0, 0, 3);
    STAGE_B(0, 0, 0); STAGE_B(0, 0, 1);
    STAGE_A(1, 1, 0); STAGE_A(1, 1, 1); STAGE_A(1, 1, 2); STAGE_A(1, 1, 3);
    STAGE_B(1, 1, 0); STAGE_B(1, 1, 1);
    asm volatile("s_waitcnt vmcnt(6)" ::: "memory");   // S(0) landed; S(1) in flight
    __builtin_amdgcn_s_barrier();

    const int NT = INFEAT / 128;   // 32
    int c = 0;
    for (int t = 0; t < NT; ++t) {
        const int cn = (c >= 1) ? c - 1 : 2;   // (c+2)%3 : target of S(t+2)
        const unsigned char* Ab = Als[c];
        const unsigned char* Bb = Bls[c];
        const bool pf = (t + 2 < NT);
        v4i af0, af1, af2, af3, bf0, bf1, bf2, bf3;

        // ---------------- phase 0 : ks=0, acc rows 0,1
        {
            const int ra0 = wm + lr,      ra1 = wm + 16 + lr;
            af0 = *(const v4i*)&Ab[ra0 * 128 + (lq ^ (ra0 & 7)) * 16];
            af1 = *(const v4i*)&Ab[ra1 * 128 + (lq ^ (ra1 & 7)) * 16];
            const int rb0 = wn + lr,      rb1 = wn + 16 + lr;
            const int rb2 = wn + 32 + lr, rb3 = wn + 48 + lr;
            bf0 = *(const v4i*)&Bb[rb0 * 128 + (lq ^ (rb0 & 7)) * 16];
            bf1 = *(const v4i*)&Bb[rb1 * 128 + (lq ^ (rb1 & 7)) * 16];
            bf2 = *(const v4i*)&Bb[rb2 * 128 + (lq ^ (rb2 & 7)) * 16];
            bf3 = *(const v4i*)&Bb[rb3 * 128 + (lq ^ (rb3 & 7)) * 16];
            if (pf) { STAGE_A(t + 2, cn, 0); STAGE_A(t + 2, cn, 1); }
            __builtin_amdgcn_s_barrier();
            asm volatile("s_waitcnt lgkmcnt(0)" ::: "memory");
            __builtin_amdgcn_sched_barrier(0);
            __builtin_amdgcn_s_setprio(1);
            MFMA_I8(acc[0][0], af0, bf0); MFMA_I8(acc[0][1], af0, bf1);
            MFMA_I8(acc[0][2], af0, bf2); MFMA_I8(acc[0][3], af0, bf3);
            MFMA_I8(acc[1][0], af1, bf0); MFMA_I8(acc[1][1], af1, bf1);
            MFMA_I8(acc[1][2], af1, bf2); MFMA_I8(acc[1][3], af1, bf3);
            __builtin_amdgcn_s_setprio(0);
            __builtin_amdgcn_s_barrier();
        }
        // ---------------- phase 1 : ks=0, acc rows 2,3 (bf reused)
        {
            const int ra2 = wm + 32 + lr, ra3 = wm + 48 + lr;
            af2 = *(const v4i*)&Ab[ra2 * 128 + (lq ^ (ra2 & 7)) * 16];
            af3 = *(const v4i*)&Ab[ra3 * 128 + (lq ^ (ra3 & 7)) * 16];
            if (pf) { STAGE_A(t + 2, cn, 2); STAGE_A(t + 2, cn, 3); }
            __builtin_amdgcn_s_barrier();
            asm volatile("s_waitcnt lgkmcnt(0)" ::: "memory");
            __builtin_amdgcn_sched_barrier(0);
            __builtin_amdgcn_s_setprio(1);
            MFMA_I8(acc[2][0], af2, bf0); MFMA_I8(acc[2][1], af2, bf1);
            MFMA_I8(acc[2][2], af2, bf2); MFMA_I8(acc[2][3], af2, bf3);
            MFMA_I8(acc[3][0], af3, bf0); MFMA_I8(acc[3][1], af3, bf1);
            MFMA_I8(acc[3][2], af3, bf2); MFMA_I8(acc[3][3], af3, bf3);
            __builtin_amdgcn_s_setprio(0);
            __builtin_amdgcn_s_barrier();
        }
        // ---------------- phase 2 : ks=1, acc rows 0,1
        {
            const int ra0 = wm + lr,      ra1 = wm + 16 + lr;
            af0 = *(const v4i*)&Ab[ra0 * 128 + ((4 + lq) ^ (ra0 & 7)) * 16];
            af1 = *(const v4i*)&Ab[ra1 * 128 + ((4 + lq) ^ (ra1 & 7)) * 16];
            const int rb0 = wn + lr,      rb1 = wn + 16 + lr;
            const int rb2 = wn + 32 + lr, rb3 = wn + 48 + lr;
            bf0 = *(const v4i*)&Bb[rb0 * 128 + ((4 + lq) ^ (rb0 & 7)) * 16];
            bf1 = *(const v4i*)&Bb[rb1 * 128 + ((4 + lq) ^ (rb1 & 7)) * 16];
            bf2 = *(const v4i*)&Bb[rb2 * 128 + ((4 + lq) ^ (rb2 & 7)) * 16];
            bf3 = *(const v4i*)&Bb[rb3 * 128 + ((4 + lq) ^ (rb3 & 7)) * 16];
            if (pf) { STAGE_B(t + 2, cn, 0); }
            __builtin_amdgcn_s_barrier();
            asm volatile("s_waitcnt lgkmcnt(0)" ::: "memory");
            __builtin_amdgcn_sched_barrier(0);
            __builtin_amdgcn_s_setprio(1);
            MFMA_I8(acc[0][0], af0, bf0); MFMA_I8(acc[0][1], af0, bf1);
            MFMA_I8(acc[0][2], af0, bf2); MFMA_I8(acc[0][3], af0, bf3);
            MFMA_I8(acc[1][0], af1, bf0); MFMA_I8(acc[1][1], af1, bf1);
            MFMA_I8(acc[1][2], af1, bf2); MFMA_I8(acc[1][3], af1, bf3);
            __builtin_amdgcn_s_setprio(0);
            __builtin_amdgcn_s_barrier();
        }
        // ---------------- phase 3 : ks=1, acc rows 2,3; counted vmcnt
        {
            const int ra2 = wm + 32 + lr, ra3 = wm + 48 + lr;
            af2 = *(const v4i*)&Ab[ra2 * 128 + ((4 + lq) ^ (ra2 & 7)) * 16];
            af3 = *(const v4i*)&Ab[ra3 * 128 + ((4 + lq) ^ (ra3 & 7)) * 16];
            if (pf) { STAGE_B(t + 2, cn, 1); }
            __builtin_amdgcn_s_barrier();
            asm volatile("s_waitcnt lgkmcnt(0)" ::: "memory");
            __builtin_amdgcn_sched_barrier(0);
            __builtin_amdgcn_s_setprio(1);
            MFMA_I8(acc[2][0], af2, bf0); MFMA_I8(acc[2][1], af2, bf1);
            MFMA_I8(acc[2][2], af2, bf2); MFMA_I8(acc[2][3], af2, bf3);
            MFMA_I8(acc[3][0], af3, bf0); MFMA_I8(acc[3][1], af3, bf1);
            MFMA_I8(acc[3][2], af3, bf2); MFMA_I8(acc[3][3], af3, bf3);
            __builtin_amdgcn_s_setprio(0);
            // steady state: 6 newest outstanding = S(t+2); <=6 left => S(t+1) landed.
            if (t < NT - 2) { asm volatile("s_waitcnt vmcnt(6)" ::: "memory"); }
            else            { asm volatile("s_waitcnt vmcnt(0)" ::: "memory"); }
            __builtin_amdgcn_sched_barrier(0);
            __builtin_amdgcn_s_barrier();
        }
        c = (c == 2) ? 0 : c + 1;
    }

    // epilogue: out = sx[m]*s[n]*(acc + (128-z[n])*xsum[m]) + bias[n]
    #pragma unroll
    for (int j = 0; j < 4; ++j) {
        const int col = n0 + wn + j * 16 + lr;
        const float sn = scales[col];
        const int zi = 128 - zeros[col];
        const float bv = bias[col];
        #pragma unroll
        for (int i = 0; i < 4; ++i) {
            const int rb = m0 + wm + i * 16 + lq * 4;
            #pragma unroll
            for (int r = 0; r < 4; ++r) {
                const int tot = acc[i][j][r] + zi * xsum[rb + r];
                out[(size_t)(rb + r) * OUTFEAT + col] = xscale[rb + r] * sn * (float)tot + bv;
            }
        }
    }
#undef STAGE_A
#undef STAGE_B
}

// ---------------- fallback (round-1 fused kernel, used if ws too small) ----
#define LDSS 72
__global__ __launch_bounds__(256) void q3gemm_fb(
    const float* __restrict__ x, const unsigned int* __restrict__ qw,
    const float* __restrict__ scales, const int* __restrict__ zeros,
    const float* __restrict__ bias, float* __restrict__ out)
{
    __shared__ bf16_t Als[128 * LDSS];
    __shared__ bf16_t Bls[128 * LDSS];
    const int tid = threadIdx.x;
    const int m0 = blockIdx.y * 128;
    const int n0 = blockIdx.x * 128;
    const int bcol = tid & 127;
    const int bpr  = tid >> 7;
    const float scf = scales[n0 + bcol];
    const float nzs = (float)zeros[n0 + bcol] * scf;
    const int acolg = tid & 15;
    const int arow0 = tid >> 4;
    const int wid  = tid >> 6;
    const int lane = tid & 63;
    const int wm = (wid & 1) * 64;
    const int wn = (wid >> 1) * 64;
    const int lr = lane & 15;
    const int lq = lane >> 4;
    f32x4 acc[4][4];
    #pragma unroll
    for (int i = 0; i < 4; ++i)
        #pragma unroll
        for (int j = 0; j < 4; ++j) acc[i][j] = (f32x4)0.0f;
    for (int kt = 0; kt < INFEAT / 64; ++kt) {
        const int k0 = kt * 64;
        #pragma unroll
        for (int p = 0; p < 8; ++p) {
            const int row = arow0 + p * 16;
            const float4 v = *(const float4*)&x[(size_t)(m0 + row) * INFEAT + k0 + acolg * 4];
            bf16x4 b;
            b[0] = (bf16_t)v.x; b[1] = (bf16_t)v.y; b[2] = (bf16_t)v.z; b[3] = (bf16_t)v.w;
            *(bf16x4*)&Als[row * LDSS + acolg * 4] = b;
        }
        const int kp0 = k0 >> 2;
        #pragma unroll
        for (int it = 0; it < 8; ++it) {
            const int prel = it * 2 + bpr;
            const unsigned int q = qw[(size_t)(kp0 + prel) * OUTFEAT + n0 + bcol];
            bf16x4 b;
            b[0] = (bf16_t)((float)(q & 0xFFu)        * scf - nzs);
            b[1] = (bf16_t)((float)((q >> 8) & 0xFFu) * scf - nzs);
            b[2] = (bf16_t)((float)((q >> 16) & 0xFFu)* scf - nzs);
            b[3] = (bf16_t)((float)(q >> 24)          * scf - nzs);
            *(bf16x4*)&Bls[bcol * LDSS + prel * 4] = b;
        }
        __syncthreads();
        #pragma unroll
        for (int ks = 0; ks < 2; ++ks) {
            bf16x8 af[4], bfv[4];
            #pragma unroll
            for (int t = 0; t < 4; ++t) {
                af[t]  = *(const bf16x8*)&Als[(wm + t * 16 + lr) * LDSS + ks * 32 + lq * 8];
                bfv[t] = *(const bf16x8*)&Bls[(wn + t * 16 + lr) * LDSS + ks * 32 + lq * 8];
            }
            #pragma unroll
            for (int i = 0; i < 4; ++i)
                #pragma unroll
                for (int j = 0; j < 4; ++j)
                    acc[i][j] = __builtin_amdgcn_mfma_f32_16x16x32_bf16(af[i], bfv[j], acc[i][j], 0, 0, 0);
        }
        __syncthreads();
    }
    #pragma unroll
    for (int j = 0; j < 4; ++j) {
        const int col = n0 + wn + j * 16 + lr;
        const float bv = bias[col];
        #pragma unroll
        for (int i = 0; i < 4; ++i) {
            const int rbs = m0 + wm + i * 16 + lq * 4;
            #pragma unroll
            for (int r = 0; r < 4; ++r)
                out[(size_t)(rbs + r) * OUTFEAT + col] = acc[i][j][r] + bv;
        }
    }
}

extern "C" void kernel_launch(void* const* d_in, const int* in_sizes, int n_in,
                              void* d_out, int out_size, void* d_ws, size_t ws_size,
                              hipStream_t stream) {
    const float*        x      = (const float*)d_in[0];
    const unsigned int* qw     = (const unsigned int*)d_in[1];
    const float*        scales = (const float*)d_in[2];
    const int*          zeros  = (const int*)d_in[3];
    const float*        bias   = (const float*)d_in[4];
    float*              out    = (float*)d_out;

    const size_t wt_bytes = (size_t)OUTFEAT * INFEAT;        // 45.1 MB i8 transposed weights
    const size_t xq_bytes = (size_t)TOKENS * INFEAT;         // 8.4 MB packed i8 x
    const size_t need = wt_bytes + xq_bytes + TOKENS * (sizeof(float) + sizeof(int)) + 256;

    if (ws_size >= need) {
        unsigned char* wt = (unsigned char*)d_ws;
        unsigned int* xq  = (unsigned int*)((char*)d_ws + wt_bytes);
        float* xscale = (float*)((char*)d_ws + wt_bytes + xq_bytes);
        int*   xsum   = (int*)((char*)d_ws + wt_bytes + xq_bytes + TOKENS * sizeof(float));

        prep<<<dim3(2752 + TOKENS), dim3(256), 0, stream>>>(x, qw, xq, xscale, xsum, wt);
        q3gemm_i8p<<<dim3((OUTFEAT / 128) * (TOKENS / 256)), dim3(512), 0, stream>>>(
            (const unsigned char*)xq, wt, scales, zeros, bias, xscale, xsum, out);
    } else {
        q3gemm_fb<<<dim3(OUTFEAT / 128, TOKENS / 128), dim3(256), 0, stream>>>(
            x, qw, scales, zeros, bias, out);
    }
}